// Round 7
// baseline (1358.855 us; speedup 1.0000x reference)
//
#include <hip/hip_runtime.h>
#include <hip/hip_bf16.h>
#include <math.h>

// ---------------------------------------------------------------------------
// Swin block: LN1 -> shift+window QKV attn proj +res -> LN2 -> MLP +res
// B=32 H=W=56 C=384 NH=12 HD=32 WS=7 SS=3 N=49 NW=64 M=100352 MLP_H=1536
// Round 9: resubmit of round 8 (container failed twice; kernel re-audited
//   clean: LDS/global bounds, barrier uniformity, VGPR budget, swizzle
//   involution, parity WAR/RAW all check out; 512thr+128KiB+this skeleton
//   each individually proven in rounds 3/4/5 -> infra-flake theory).
//   Only delta vs round 8: __launch_bounds__(512,1) == round 3's proven
//   resource declaration.
//   Design (unchanged): cut LDS traffic via register reuse. 8 fat waves
//   (2Mx4N), wave 64x96, acc[4][6]=96 VGPR -> per-K-tile LDS traffic
//   320->224 KB at same FLOPs/global bytes. BM=128 BN=384 BK=64, 512 thr,
//   128 KiB double-buffered LDS, parity skeleton: iter T: ds_write tile
//   T+1 -> lb[P^1]; issue global tile T+2; COMPUTE lb[P]; lgkmcnt(0);
//   s_barrier. No vmcnt drain in loop. XOR swizzle both sides.
// Workspace layout (bytes):
//   0         wt_qkv  (1152x384 bf16)
//   884736    wt_proj (384x384 bf16)
//   1179648   wt_fc1  (1536x384 bf16)
//   2359296   wt_fc2  (384x1536 bf16)
//   3538944   biasM   (12x49x49 f32)
//   3654656   xw      (100352x384 bf16)   } reused as hidden (100352x1536 bf16)
//   80724992  qkv     (100352x1152 bf16)  }
//   311936000 attn_out(100352x384 bf16)   reused as hn
// ---------------------------------------------------------------------------

typedef short bf16x8 __attribute__((ext_vector_type(8)));
typedef float f32x4 __attribute__((ext_vector_type(4)));

// ---- merged prep: 4 weight transposes (f32->bf16) + rel-pos bias matrix ----
__global__ __launch_bounds__(256) void prep_k(
    const float* __restrict__ qkvw, const float* __restrict__ projw,
    const float* __restrict__ fc1w, const float* __restrict__ fc2w,
    const float* __restrict__ rpb,
    __hip_bfloat16* __restrict__ wt_qkv, __hip_bfloat16* __restrict__ wt_proj,
    __hip_bfloat16* __restrict__ wt_fc1, __hip_bfloat16* __restrict__ wt_fc2,
    float* __restrict__ biasM) {
    int id = blockIdx.x * 256 + threadIdx.x;
    if (id < 442368) {  // qkv_w (384x1152)
        int k = id / 1152, n = id % 1152;
        wt_qkv[(size_t)n * 384 + k] = __float2bfloat16(qkvw[id]);
        return;
    }
    id -= 442368;
    if (id < 147456) {  // proj_w (384x384)
        int k = id / 384, n = id % 384;
        wt_proj[(size_t)n * 384 + k] = __float2bfloat16(projw[id]);
        return;
    }
    id -= 147456;
    if (id < 589824) {  // fc1_w (384x1536)
        int k = id / 1536, n = id % 1536;
        wt_fc1[(size_t)n * 384 + k] = __float2bfloat16(fc1w[id]);
        return;
    }
    id -= 589824;
    if (id < 589824) {  // fc2_w (1536x384)
        int k = id / 384, n = id % 384;
        wt_fc2[(size_t)n * 1536 + k] = __float2bfloat16(fc2w[id]);
        return;
    }
    id -= 589824;
    if (id < 28812) {  // biasM[h][i][j]
        int h = id / 2401, rem = id % 2401, i = rem / 49, j = rem % 49;
        int ih = i / 7, iw = i % 7, jh = j / 7, jw = j % 7;
        int idx = (ih - jh + 6) * 13 + (iw - jw + 6);
        biasM[id] = rpb[idx * 12 + h];
    }
}

// ---- LayerNorm. MODE 0: gather shifted+window-partitioned rows -> xw -------
// ---- MODE 1: plain image rows (x_res -> hn) --------------------------------
template <int MODE>
__global__ __launch_bounds__(256) void ln_k(const float* __restrict__ X,
                                            const float* __restrict__ w,
                                            const float* __restrict__ b,
                                            __hip_bfloat16* __restrict__ out) {
    int wv = threadIdx.x >> 6, lane = threadIdx.x & 63;
    int row = blockIdx.x * 4 + wv;  // output row
    size_t src_row;
    if (MODE == 0) {
        int wi = row / 49, t = row % 49;
        int bb = wi >> 6, wrem = wi & 63;
        int wh = wrem >> 3, ww = wrem & 7;
        int th = t / 7, tw = t % 7;
        int hi = (wh * 7 + th + 3) % 56;      // roll(-3): shifted[hs]=x[(hs+3)%56]
        int wimg = (ww * 7 + tw + 3) % 56;
        src_row = (size_t)(bb * 3136 + hi * 56 + wimg);
    } else {
        src_row = row;
    }
    const float* src = X + src_row * 384;
    float v[6];
    float s = 0.f, sq = 0.f;
#pragma unroll
    for (int i = 0; i < 6; i++) {
        v[i] = src[lane + i * 64];
        s += v[i];
        sq += v[i] * v[i];
    }
#pragma unroll
    for (int m = 32; m >= 1; m >>= 1) {
        s += __shfl_xor(s, m, 64);
        sq += __shfl_xor(sq, m, 64);
    }
    float mean = s * (1.f / 384.f);
    float var = sq * (1.f / 384.f) - mean * mean;
    float rstd = rsqrtf(var + 1e-5f);
    size_t orow = (size_t)row * 384;
#pragma unroll
    for (int i = 0; i < 6; i++) {
        int c = lane + i * 64;
        out[orow + c] = __float2bfloat16((v[i] - mean) * rstd * w[c] + b[c]);
    }
}

// ---- 128x384x(BK=64) bf16 MFMA GEMM, A[M,K] x Bt[N,K]^T, 512 threads -------
// 8 waves as 2(M)x4(N); per-wave 64 rows x 96 cols (acc[4][6] f32x4).
// Per K-tile 64 KB staged: A 128x64 (16KB) + B 384x64 (48KB); thread t owns
// 8 16B-chunks: A rows {row0, row0+64} + B rows row0+{0,64,...,320}, chunk
// c0 = t&7, row0 = t>>3. Parity skeleton (rounds 4/5, verified):
//   iter T (parity P): ds_write staged regs (tile T+1) -> lb[P^1];
//   issue global loads (tile T+2); COMPUTE lb[P]; lgkmcnt(0); s_barrier.
//   No vmcnt drain in loop (compiler waits precisely on staged regs).
// LDS swizzle: row r stores logical chunk q at slot q^(r&7) (write-side
// applied directly; ds_read XORs with lm&7; row&7==lm&7 for frag rows).
// EPI 0: +bias -> bf16 (qkv)        EPI 1: +bias, window-reverse+unshift,
// EPI 2: +bias, GELU -> bf16 (fc1)         +residual(x) -> f32 (proj)
// EPI 3: +bias +residual -> f32 (fc2)
template <int EPI>
__global__ __launch_bounds__(512, 1) void gemm_k(
    const __hip_bfloat16* __restrict__ A, const __hip_bfloat16* __restrict__ Bt,
    const float* __restrict__ bias, int K, int nTilesN,
    __hip_bfloat16* outb, float* outf, const float* resin) {
    __shared__ __align__(16) __hip_bfloat16 lb[2][(128 + 384) * 64];  // 128 KiB
    // chunked XCD swizzle (all grids %8==0)
    int bid = blockIdx.x;
    bid = (bid & 7) * ((int)gridDim.x >> 3) + (bid >> 3);
    int tM = bid / nTilesN, tN = bid % nTilesN;
    size_t m0 = (size_t)tM * 128;
    int n0 = tN * 384;
    int tid = threadIdx.x, wv = tid >> 6, lane = tid & 63;
    int wr = wv >> 2, wc = wv & 3;  // wave grid 2(M) x 4(N)
    int lm = lane & 15, lg = lane >> 4;

    f32x4 acc[4][6];
#pragma unroll
    for (int m = 0; m < 4; m++)
#pragma unroll
        for (int j = 0; j < 6; j++) acc[m][j] = (f32x4){0.f, 0.f, 0.f, 0.f};

    // staging: thread t covers chunk c0 of A rows {row0,row0+64} and
    // B rows row0+{0,64,...,320}
    int row0 = tid >> 3, c0 = tid & 7;
    const __hip_bfloat16* gA = A + (m0 + row0) * K + c0 * 8;
    const __hip_bfloat16* gB = Bt + (size_t)(n0 + row0) * K + c0 * 8;
    int wof = row0 * 64 + ((c0 ^ (row0 & 7)) * 8);  // swizzled write offset
    // A slots: wof, wof+4096; B slots: 8192 + wof + i*4096 (i=0..5)

    // ds_read swizzled chunk offsets (row&7 == lm&7 for all frag rows)
    int rsw0 = ((0 + lg) ^ (lm & 7)) * 8;
    int rsw1 = ((4 + lg) ^ (lm & 7)) * 8;
    int arow = (wr * 64 + lm) * 64;           // + m*1024
    int brow = 8192 + (wc * 96 + lm) * 64;    // + j*1024

    int nkt = K >> 6;  // 6 (K=384) or 24 (K=1536) -- always even

    bf16x8 st[8];  // staged regs: A x2, B x6

#define LOADT(T)                                                               \
    do {                                                                       \
        size_t k0_ = (size_t)(T) * 64;                                         \
        st[0] = *(const bf16x8*)(gA + k0_);                                    \
        st[1] = *(const bf16x8*)(gA + (size_t)64 * K + k0_);                   \
        st[2] = *(const bf16x8*)(gB + k0_);                                    \
        st[3] = *(const bf16x8*)(gB + (size_t)64 * K + k0_);                   \
        st[4] = *(const bf16x8*)(gB + (size_t)128 * K + k0_);                  \
        st[5] = *(const bf16x8*)(gB + (size_t)192 * K + k0_);                  \
        st[6] = *(const bf16x8*)(gB + (size_t)256 * K + k0_);                  \
        st[7] = *(const bf16x8*)(gB + (size_t)320 * K + k0_);                  \
    } while (0)
#define WRITET(P)                                                              \
    do {                                                                       \
        *(bf16x8*)&lb[P][wof] = st[0];                                         \
        *(bf16x8*)&lb[P][wof + 4096] = st[1];                                  \
        *(bf16x8*)&lb[P][8192 + wof] = st[2];                                  \
        *(bf16x8*)&lb[P][8192 + wof + 4096] = st[3];                           \
        *(bf16x8*)&lb[P][8192 + wof + 8192] = st[4];                           \
        *(bf16x8*)&lb[P][8192 + wof + 12288] = st[5];                          \
        *(bf16x8*)&lb[P][8192 + wof + 16384] = st[6];                          \
        *(bf16x8*)&lb[P][8192 + wof + 20480] = st[7];                          \
    } while (0)
#define COMPUTE(P)                                                             \
    do {                                                                       \
        bf16x8 af[4][2];                                                       \
        _Pragma("unroll") for (int m = 0; m < 4; m++) {                        \
            af[m][0] = *(const bf16x8*)&lb[P][arow + m * 1024 + rsw0];         \
            af[m][1] = *(const bf16x8*)&lb[P][arow + m * 1024 + rsw1];         \
        }                                                                      \
        _Pragma("unroll") for (int j = 0; j < 6; j++) {                        \
            bf16x8 b0 = *(const bf16x8*)&lb[P][brow + j * 1024 + rsw0];        \
            bf16x8 b1 = *(const bf16x8*)&lb[P][brow + j * 1024 + rsw1];        \
            _Pragma("unroll") for (int m = 0; m < 4; m++) {                    \
                acc[m][j] = __builtin_amdgcn_mfma_f32_16x16x32_bf16(           \
                    af[m][0], b0, acc[m][j], 0, 0, 0);                         \
                acc[m][j] = __builtin_amdgcn_mfma_f32_16x16x32_bf16(           \
                    af[m][1], b1, acc[m][j], 0, 0, 0);                         \
            }                                                                  \
        }                                                                      \
    } while (0)
#define ENDBAR()                                                               \
    do {                                                                       \
        asm volatile("s_waitcnt lgkmcnt(0)" ::: "memory");                     \
        __builtin_amdgcn_sched_barrier(0);                                     \
        __builtin_amdgcn_s_barrier();                                          \
        __builtin_amdgcn_sched_barrier(0);                                     \
    } while (0)
#define ITER(P, T)                                                             \
    do {                                                                       \
        if ((T) + 1 < nkt) WRITET(P ^ 1);                                      \
        if ((T) + 2 < nkt) LOADT((T) + 2);                                     \
        COMPUTE(P);                                                            \
        ENDBAR();                                                              \
    } while (0)

    // prologue: tile 0 -> lb[0]; tile 1 staged in regs
    LOADT(0);
    WRITET(0);  // compiler inserts precise vmcnt wait for st
    LOADT(1);
    ENDBAR();

    for (int t = 0; t < nkt; t += 2) {
        ITER(0, t);
        ITER(1, t + 1);
    }
#undef ITER
#undef ENDBAR
#undef COMPUTE
#undef WRITET
#undef LOADT

    int ld = nTilesN * 384;
#pragma unroll
    for (int m = 0; m < 4; m++) {
#pragma unroll
        for (int r = 0; r < 4; r++) {
            int row = (int)m0 + wr * 64 + m * 16 + lg * 4 + r;
#pragma unroll
            for (int j = 0; j < 6; j++) {
                int col = n0 + wc * 96 + j * 16 + lm;
                float val = acc[m][j][r] + bias[col];
                if (EPI == 0) {
                    outb[(size_t)row * ld + col] = __float2bfloat16(val);
                } else if (EPI == 2) {
                    float g = 0.5f * val * (1.f + erff(val * 0.70710678118f));
                    outb[(size_t)row * ld + col] = __float2bfloat16(g);
                } else if (EPI == 1) {
                    // window-reverse + unshift + residual: row -> image pos
                    int wi = row / 49, t = row % 49;
                    int bb = wi >> 6, wrem = wi & 63;
                    int wh = wrem >> 3, ww = wrem & 7;
                    int th = t / 7, tw = t % 7;
                    int hi = (wh * 7 + th + 3) % 56;
                    int wimg = (ww * 7 + tw + 3) % 56;
                    size_t pos = (size_t)(bb * 3136 + hi * 56 + wimg) * 384 + col;
                    outf[pos] = resin[pos] + val;
                } else {  // EPI 3
                    size_t pos = (size_t)row * 384 + col;
                    outf[pos] = resin[pos] + val;
                }
            }
        }
    }
}

// ---- windowed attention: one block per (window, head) ----------------------
// LDS rows padded to 72 elems (144 B) -> 2-way bank access (free).
__global__ __launch_bounds__(256) void attn_k(const __hip_bfloat16* __restrict__ qkv,
                                              const float* __restrict__ biasM,
                                              __hip_bfloat16* __restrict__ out) {
    __shared__ __align__(16) __hip_bfloat16 vt[32 * 72];  // [dim][token(+pad)]
    __shared__ __align__(16) __hip_bfloat16 P[64 * 72];   // softmax probs
    // chunked XCD swizzle: 12 heads of a window share its qkv rows in L2
    int bid = blockIdx.x;
    bid = (bid & 7) * ((int)gridDim.x >> 3) + (bid >> 3);
    int wi = bid / 12, h = bid % 12;
    int tid = threadIdx.x, wv = tid >> 6, lane = tid & 63;
    int lm = lane & 15, lg = lane >> 4;
    int wrem = wi & 63, wh = wrem >> 3, ww = wrem & 7;

    // zero vt (covers token pad 49..71)
#pragma unroll
    for (int i = 0; i < 9; i++) vt[tid * 9 + i] = __float2bfloat16(0.f);
    __syncthreads();
    // stage v transposed: vt[d][t] = v[t][d]
    if (tid < 196) {
        int t = tid >> 2, d0 = (tid & 3) * 8;
        bf16x8 vv = *(const bf16x8*)(qkv + (size_t)(wi * 49 + t) * 1152 + 768 + h * 32 + d0);
#pragma unroll
        for (int i = 0; i < 8; i++) vt[(d0 + i) * 72 + t] = ((__hip_bfloat16*)&vv)[i];
    }

    // S = q @ k^T  (wave wv owns row-tile wv; frags straight from global)
    int qrow = wv * 16 + lm;
    if (qrow > 48) qrow = 48;
    bf16x8 aq = *(const bf16x8*)(qkv + (size_t)(wi * 49 + qrow) * 1152 + h * 32 + lg * 8);
    f32x4 S[4];
#pragma unroll
    for (int ct = 0; ct < 4; ct++) {
        int krow = ct * 16 + lm;
        if (krow > 48) krow = 48;
        bf16x8 bk = *(const bf16x8*)(qkv + (size_t)(wi * 49 + krow) * 1152 + 384 + h * 32 + lg * 8);
        S[ct] = __builtin_amdgcn_mfma_f32_16x16x32_bf16(aq, bk, (f32x4){0.f, 0.f, 0.f, 0.f}, 0, 0, 0);
    }

    // scale + rel-pos bias + shift mask + row softmax -> P (bf16, LDS)
    const float scale = 0.17677669529663687f;  // 32^-0.5
#pragma unroll
    for (int r = 0; r < 4; r++) {
        int irow = wv * 16 + lg * 4 + r;
        int ic = irow <= 48 ? irow : 48;
        int ith = ic / 7, itw = ic % 7;
        int ihs = wh * 7 + ith, iws = ww * 7 + itw;
        int ridi = (ihs < 49 ? 0 : (ihs < 53 ? 1 : 2)) * 3 + (iws < 49 ? 0 : (iws < 53 ? 1 : 2));
        float vals[4];
        float mx = -1e30f;
#pragma unroll
        for (int ct = 0; ct < 4; ct++) {
            int jcol = ct * 16 + lm;
            float sv;
            if (jcol < 49) {
                int jth = jcol / 7, jtw = jcol % 7;
                int jhs = wh * 7 + jth, jws = ww * 7 + jtw;
                int ridj = (jhs < 49 ? 0 : (jhs < 53 ? 1 : 2)) * 3 + (jws < 49 ? 0 : (jws < 53 ? 1 : 2));
                sv = S[ct][r] * scale + biasM[h * 2401 + ic * 49 + jcol] +
                     (ridi != ridj ? -100.f : 0.f);
            } else {
                sv = -1e30f;  // pad cols -> prob 0
            }
            vals[ct] = sv;
            mx = fmaxf(mx, sv);
        }
#pragma unroll
        for (int m = 8; m >= 1; m >>= 1) mx = fmaxf(mx, __shfl_xor(mx, m, 64));
        float sum = 0.f;
#pragma unroll
        for (int ct = 0; ct < 4; ct++) {
            vals[ct] = __expf(vals[ct] - mx);
            sum += vals[ct];
        }
#pragma unroll
        for (int m = 8; m >= 1; m >>= 1) sum += __shfl_xor(sum, m, 64);
        float inv = 1.f / sum;
#pragma unroll
        for (int ct = 0; ct < 4; ct++)
            P[irow * 72 + ct * 16 + lm] = __float2bfloat16(vals[ct] * inv);
    }
    __syncthreads();

    // O = P @ v   (K=64 = two 32-steps; N=32 = two col-tiles)
    f32x4 O[2] = {{0.f, 0.f, 0.f, 0.f}, {0.f, 0.f, 0.f, 0.f}};
#pragma unroll
    for (int ks = 0; ks < 2; ks++) {
        bf16x8 ap = *(const bf16x8*)&P[(wv * 16 + lm) * 72 + ks * 32 + lg * 8];
#pragma unroll
        for (int nt = 0; nt < 2; nt++) {
            bf16x8 bv = *(const bf16x8*)&vt[(nt * 16 + lm) * 72 + ks * 32 + lg * 8];
            O[nt] = __builtin_amdgcn_mfma_f32_16x16x32_bf16(ap, bv, O[nt], 0, 0, 0);
        }
    }
#pragma unroll
    for (int r = 0; r < 4; r++) {
        int row = wv * 16 + lg * 4 + r;
        if (row < 49) {
            size_t base = (size_t)(wi * 49 + row) * 384 + h * 32;
            out[base + lm] = __float2bfloat16(O[0][r]);
            out[base + 16 + lm] = __float2bfloat16(O[1][r]);
        }
    }
}

extern "C" void kernel_launch(void* const* d_in, const int* in_sizes, int n_in,
                              void* d_out, int out_size, void* d_ws, size_t ws_size,
                              hipStream_t stream) {
    (void)in_sizes; (void)n_in; (void)out_size; (void)ws_size;
    const float* x     = (const float*)d_in[0];
    const float* n1w   = (const float*)d_in[1];
    const float* n1b   = (const float*)d_in[2];
    const float* qkvw  = (const float*)d_in[3];
    const float* qkvb  = (const float*)d_in[4];
    const float* rpb   = (const float*)d_in[5];
    const float* projw = (const float*)d_in[6];
    const float* projb = (const float*)d_in[7];
    const float* n2w   = (const float*)d_in[8];
    const float* n2b   = (const float*)d_in[9];
    const float* fc1w  = (const float*)d_in[10];
    const float* fc1b  = (const float*)d_in[11];
    const float* fc2w  = (const float*)d_in[12];
    const float* fc2b  = (const float*)d_in[13];
    float* out = (float*)d_out;

    char* ws = (char*)d_ws;
    __hip_bfloat16* wt_qkv  = (__hip_bfloat16*)(ws + 0);
    __hip_bfloat16* wt_proj = (__hip_bfloat16*)(ws + 884736);
    __hip_bfloat16* wt_fc1  = (__hip_bfloat16*)(ws + 1179648);
    __hip_bfloat16* wt_fc2  = (__hip_bfloat16*)(ws + 2359296);
    float*          biasM   = (float*)(ws + 3538944);
    __hip_bfloat16* xw      = (__hip_bfloat16*)(ws + 3654656);
    __hip_bfloat16* qkv     = (__hip_bfloat16*)(ws + 80724992);
    __hip_bfloat16* attn_o  = (__hip_bfloat16*)(ws + 311936000);
    __hip_bfloat16* hidden  = xw;      // reuse xw+qkv region (308 MB)
    __hip_bfloat16* hn      = attn_o;  // reuse attn_out region

    // merged weight-convert + bias-matrix prep (1,798,284 elements)
    prep_k<<<7025, 256, 0, stream>>>(qkvw, projw, fc1w, fc2w, rpb,
                                     wt_qkv, wt_proj, wt_fc1, wt_fc2, biasM);

    // LN1 + cyclic shift + window partition
    ln_k<0><<<25088, 256, 0, stream>>>(x, n1w, n1b, xw);
    // QKV projection (grid 2352 % 8 == 0)
    gemm_k<0><<<784 * 3, 512, 0, stream>>>(xw, wt_qkv, qkvb, 384, 3, qkv, nullptr, nullptr);
    // windowed attention (grid 24576 % 8 == 0)
    attn_k<<<2048 * 12, 256, 0, stream>>>(qkv, biasM, attn_o);
    // proj + window reverse + unshift + residual -> x_res (in d_out, fp32)
    gemm_k<1><<<784, 512, 0, stream>>>(attn_o, wt_proj, projb, 384, 1, nullptr, out, x);
    // LN2
    ln_k<1><<<25088, 256, 0, stream>>>(out, n2w, n2b, hn);
    // fc1 + GELU (grid 3136 % 8 == 0)
    gemm_k<2><<<784 * 4, 512, 0, stream>>>(hn, wt_fc1, fc1b, 384, 4, hidden, nullptr, nullptr);
    // fc2 + residual -> d_out
    gemm_k<3><<<784, 512, 0, stream>>>(hidden, wt_fc2, fc2b, 1536, 1, nullptr, out, out);
}